// Round 1
// baseline (105.969 us; speedup 1.0000x reference)
//
#include <hip/hip_runtime.h>

#define HORIZON 10
#define NUM_REGIONS 64
#define BB 32
#define TT 12
#define NN 100000

// Kernel A: per (b, node-pair) — time-mean of feature 0, write 10 horizon
// copies, accumulate per-region sums via LDS -> global atomics.
__global__ __launch_bounds__(256) void mean_kernel(
    const float* __restrict__ x, const int* __restrict__ cid,
    float* __restrict__ out0, float* __restrict__ gsum)
{
    __shared__ float lsum[NUM_REGIONS];
    const int tid = threadIdx.x;
    if (tid < NUM_REGIONS) lsum[tid] = 0.0f;
    __syncthreads();

    const int b = blockIdx.y;
    const int i = blockIdx.x * blockDim.x + tid;   // pair index: nodes 2i, 2i+1
    const int n0 = 2 * i;
    if (n0 < NN) {
        float s0 = 0.0f, s1 = 0.0f;
        #pragma unroll
        for (int t = 0; t < TT; ++t) {
            const float4 v = *reinterpret_cast<const float4*>(
                x + ((size_t)(b * TT + t) * NN + n0) * 2);
            s0 += v.x;   // feature 0 of node n0
            s1 += v.z;   // feature 0 of node n0+1
        }
        const float m0 = s0 * (1.0f / 12.0f);
        const float m1 = s1 * (1.0f / 12.0f);
        const float2 mv = make_float2(m0, m1);
        const size_t obase = (size_t)b * HORIZON * NN + n0;
        #pragma unroll
        for (int h = 0; h < HORIZON; ++h) {
            *reinterpret_cast<float2*>(out0 + obase + (size_t)h * NN) = mv;
        }
        atomicAdd(&lsum[cid[n0]], m0);
        atomicAdd(&lsum[cid[n0 + 1]], m1);
    }
    __syncthreads();
    if (tid < NUM_REGIONS) {
        atomicAdd(&gsum[b * NUM_REGIONS + tid], lsum[tid]);
    }
}

// Kernel B: region counts.
__global__ __launch_bounds__(256) void count_kernel(
    const int* __restrict__ cid, float* __restrict__ gcount)
{
    __shared__ float lc[NUM_REGIONS];
    const int tid = threadIdx.x;
    if (tid < NUM_REGIONS) lc[tid] = 0.0f;
    __syncthreads();
    const int n = blockIdx.x * blockDim.x + tid;
    if (n < NN) atomicAdd(&lc[cid[n]], 1.0f);
    __syncthreads();
    if (tid < NUM_REGIONS) atomicAdd(&gcount[tid], lc[tid]);
}

// Kernel C: regional means broadcast over horizon.
__global__ __launch_bounds__(256) void finalize_kernel(
    const float* __restrict__ gsum, const float* __restrict__ gcount,
    float* __restrict__ out1)
{
    const int idx = blockIdx.x * blockDim.x + threadIdx.x;  // 0 .. B*R-1
    if (idx >= BB * NUM_REGIONS) return;
    const int b = idx >> 6;
    const int r = idx & 63;
    const float v = gsum[idx] / gcount[r];
    const size_t base = (size_t)b * HORIZON * NUM_REGIONS + r;
    #pragma unroll
    for (int h = 0; h < HORIZON; ++h) {
        out1[base + (size_t)h * NUM_REGIONS] = v;
    }
}

extern "C" void kernel_launch(void* const* d_in, const int* in_sizes, int n_in,
                              void* d_out, int out_size, void* d_ws, size_t ws_size,
                              hipStream_t stream) {
    const float* x   = (const float*)d_in[0];
    const int*   cid = (const int*)d_in[1];
    float* out0 = (float*)d_out;
    float* out1 = out0 + (size_t)BB * HORIZON * NN;

    float* gsum   = (float*)d_ws;                 // BB*NUM_REGIONS floats
    float* gcount = gsum + BB * NUM_REGIONS;      // NUM_REGIONS floats

    hipMemsetAsync(d_ws, 0,
                   (BB * NUM_REGIONS + NUM_REGIONS) * sizeof(float), stream);

    dim3 gridA((NN / 2 + 255) / 256, BB);
    mean_kernel<<<gridA, 256, 0, stream>>>(x, cid, out0, gsum);

    count_kernel<<<(NN + 255) / 256, 256, 0, stream>>>(cid, gcount);

    finalize_kernel<<<(BB * NUM_REGIONS + 255) / 256, 256, 0, stream>>>(
        gsum, gcount, out1);
}